// Round 7
// baseline (140.978 us; speedup 1.0000x reference)
//
#include <hip/hip_runtime.h>

typedef _Float16 f16;
typedef _Float16 f16x8 __attribute__((ext_vector_type(8)));
typedef __bf16 bf16x8 __attribute__((ext_vector_type(8)));
typedef float floatx4 __attribute__((ext_vector_type(4)));
typedef unsigned short u16;

#define B_N   8
#define T_SEQ 4096
#define DIM   64
#define QT    64     // q rows per attn block
#define NIT   32     // 4096 / (128 keys per iter: 32 per wave x 4 key-subgroup waves)
#define XSTR  72     // prep LDS row stride in u16
#define LOG2E 1.44269504f
#define FRAG  512    // fragment = 512 u16 (1 KB): lane holds its 8 u16 at lane*8

#if __has_builtin(__builtin_amdgcn_exp2f)
#define EXP2(x) __builtin_amdgcn_exp2f(x)
#else
#define EXP2(x) exp2f(x)
#endif

typedef __attribute__((address_space(1))) const void gvoid;
typedef __attribute__((address_space(3))) void svoid;

// ---- prep v2: 32-row blocks, wave-specialized roles. Unchanged from round 6. ----
__launch_bounds__(256, 4)
__global__ void prep_kernel(const float* __restrict__ X, const float* __restrict__ W,
                            u16* __restrict__ Kswz, u16* __restrict__ Qswz,
                            u16* __restrict__ Vswz) {
  __shared__ __attribute__((aligned(16))) u16 Xs[32 * XSTR];      // f16 X tile [t][d]
  __shared__ __attribute__((aligned(16))) u16 Wt[DIM * XSTR];     // f16 W^T [e][d]
  __shared__ __attribute__((aligned(16))) u16 Qs[2][16 * XSTR];   // f16 Q rows (per Q-wave)
  const int tid = threadIdx.x;
  const int lane = tid & 63, w = tid >> 6, qd = lane >> 4, ln = lane & 15;
  const int b = blockIdx.y;
  const int tau = blockIdx.x;                 // global 32-row tile index, 0..127
  const long xbase = ((long)b * T_SEQ + tau * 32) * DIM;

  {
    // X tile: 32 rows x 64 cols, 8 f32 per thread
    const int r = tid >> 3, c0 = (tid & 7) * 8;
    float v[8];
    *(float4*)&v[0] = *(const float4*)(X + xbase + (long)r * DIM + c0);
    *(float4*)&v[4] = *(const float4*)(X + xbase + (long)r * DIM + c0 + 4);
    u16 h[8];
#pragma unroll
    for (int j = 0; j < 8; j++) h[j] = __builtin_bit_cast(u16, (f16)v[j]);
    *(uint4*)&Xs[r * XSTR + c0] = *(uint4*)&h[0];
    // W: 64x64, 16 f32 per thread, transposed scalar stores
    const int r2 = tid >> 2, c2 = (tid & 3) * 16;
    float wv[16];
#pragma unroll
    for (int i = 0; i < 4; i++)
      *(float4*)&wv[i * 4] = *(const float4*)(W + r2 * DIM + c2 + i * 4);
#pragma unroll
    for (int j = 0; j < 16; j++) Wt[(c2 + j) * XSTR + r2] = __builtin_bit_cast(u16, (f16)wv[j]);
  }
  __syncthreads();

  if (w == 0) {
    // K fragments, SLOT-PERMUTED: frag (tau, ct), lane ln reads tile-local row
    // krow = (ln>>2)*8 + ct*4 + (ln&3).
#pragma unroll
    for (int ct = 0; ct < 2; ct++) {
      const int krow = (ln >> 2) * 8 + ct * 4 + (ln & 3);
      const long F = ((long)b * 128 + tau) * 2 + ct;
#pragma unroll
      for (int ks = 0; ks < 2; ks++) {
        f16x8 kv = *(const f16x8*)&Xs[krow * XSTR + ks * 32 + qd * 8];
        *(f16x8*)(Kswz + (F * 2 + ks) * FRAG + lane * 8) = kv;
      }
    }
    // V d-block 0
    {
      const long Cb = (long)b * 4 + 0;
      bf16x8 vv;
#pragma unroll
      for (int j = 0; j < 8; j++) {
        f16 hv = __builtin_bit_cast(f16, Xs[(qd * 8 + j) * XSTR + 0 * 16 + ln]);
        vv[j] = (__bf16)(float)hv;
      }
      *(bf16x8*)(Vswz + (Cb * (T_SEQ / 32) + tau) * FRAG + lane * 8) = vv;
    }
  } else if (w == 1) {
    // V d-blocks 1..3
#pragma unroll
    for (int db = 1; db < 4; db++) {
      const long Cb = (long)b * 4 + db;
      bf16x8 vv;
#pragma unroll
      for (int j = 0; j < 8; j++) {
        f16 hv = __builtin_bit_cast(f16, Xs[(qd * 8 + j) * XSTR + db * 16 + ln]);
        vv[j] = (__bf16)(float)hv;
      }
      *(bf16x8*)(Vswz + (Cb * (T_SEQ / 32) + tau) * FRAG + lane * 8) = vv;
    }
  } else {
    // Q rows (w-2)*16 .. +16: X@W via MFMA, scale by log2e, emit A-fragments
    const int h2 = w - 2;             // 0..1
    const int rq = h2 * 16;
    floatx4 acc[4];
#pragma unroll
    for (int ct = 0; ct < 4; ct++) acc[ct] = (floatx4)0.0f;
#pragma unroll
    for (int ks = 0; ks < 2; ks++) {
      f16x8 aX = *(const f16x8*)&Xs[(rq + ln) * XSTR + ks * 32 + qd * 8];
#pragma unroll
      for (int ct = 0; ct < 4; ct++) {
        f16x8 bW = *(const f16x8*)&Wt[(ct * 16 + ln) * XSTR + ks * 32 + qd * 8];
        acc[ct] = __builtin_amdgcn_mfma_f32_16x16x32_f16(aX, bW, acc[ct], 0, 0, 0);
      }
    }
#pragma unroll
    for (int ct = 0; ct < 4; ct++)
#pragma unroll
      for (int r = 0; r < 4; r++)
        Qs[h2][(qd * 4 + r) * XSTR + ct * 16 + ln] =
            __builtin_bit_cast(u16, (f16)(acc[ct][r] * LOG2E));
    // wave-local rows: no barrier needed
    const long R = (long)b * (T_SEQ / 16) + tau * 2 + h2;
#pragma unroll
    for (int ks = 0; ks < 2; ks++) {
      f16x8 qv = *(const f16x8*)&Qs[h2][ln * XSTR + ks * 32 + qd * 8];
      *(f16x8*)(Qswz + (R * 2 + ks) * FRAG + lane * 8) = qv;
    }
  }
}

// ---- main: 8 waves = 2 q-groups x 4 key-subgroups. K/V staged to LDS via
// global_load_lds (double-buffered, 1 barrier/iter). P in registers.
// ROUND 7: software-pipelined — PV(t-1) runs at the TOP of iter t (register-
// only MFMA fills the matrix pipe while ds_reads of tile t are in flight, and
// exp(t) no longer blocks PV(t) in the same iter). pk/bV double-buffered in
// registers via explicit A/B sets (rule #20: all indices compile-time).
// Round-4 lesson: runtime-indexed reg arrays -> scratch -> 1 GB phantom writes.
__launch_bounds__(512, 4)
__global__ void attn_kernel(const u16* __restrict__ Kswz, const u16* __restrict__ Qswz,
                            const u16* __restrict__ Vswz, float* __restrict__ out) {
  // staging: per buf 32 KB = 16 K-frags (16 KB) + 16 V-frags (16 KB), 1 KB each
  __shared__ __attribute__((aligned(16))) char sbuf[2][32768];
  __shared__ float lpart[8][32];
  float* Opart = (float*)&sbuf[0][0];  // epilogue alias: 8*16*68*4 = 34816 B <= 65536

  const int tid = threadIdx.x;
  const int lane = tid & 63;
  const int w = tid >> 6;           // 0..7
  const int qd = lane >> 4;
  const int ln = lane & 15;
  const int wg = w >> 2;            // q-group
  const int wk = w & 3;             // key subgroup
  const int bid = blockIdx.x;
  const int b = bid & 7;            // batch == XCD for L2 affinity
  const int q0 = (bid >> 3) * QT;
  const long bbase = (long)b * T_SEQ * DIM;

  // Q B-fragments pinned: 32 rows x 64 d for this q-group
  f16x8 aQ[2][2];
#pragma unroll
  for (int rb = 0; rb < 2; rb++)
#pragma unroll
    for (int ks = 0; ks < 2; ks++)
      aQ[rb][ks] = *(const f16x8*)(Qswz +
          (((long)b * (T_SEQ / 16) + (q0 >> 4) + wg * 2 + rb) * 2 + ks) * FRAG + lane * 8);

  // staging source bases (per-lane byte pointers)
  const char* gKw = (const char*)Kswz + (long)b * 524288 + (long)w * 4096 + lane * 16;
  const char* gVw = (const char*)Vswz + (long)b * 524288 + (long)(w - 4) * 1024 + lane * 16;

#define STAGE(bufv, t)                                                                  \
  do {                                                                                  \
    if (w < 4) {                                                                        \
      const char* g = gKw + (long)(t) * 16384;                                          \
      char* l = &sbuf[bufv][w * 4096];                                                  \
      _Pragma("unroll") for (int i = 0; i < 4; i++)                                     \
          __builtin_amdgcn_global_load_lds((gvoid*)(g + i * 1024), (svoid*)(l + i * 1024), \
                                           16, 0, 0);                                   \
    } else {                                                                            \
      const char* g = gVw + (long)(t) * 4096;                                           \
      char* l = &sbuf[bufv][16384 + (w - 4) * 4096];                                    \
      _Pragma("unroll") for (int i = 0; i < 4; i++)                                     \
          __builtin_amdgcn_global_load_lds((gvoid*)(g + i * 131072), (svoid*)(l + i * 1024), \
                                           16, 0, 0);                                   \
    }                                                                                   \
  } while (0)

  floatx4 O[2][4];                  // [q 16-block][d 16-block], 32q x 64d per wave
  float lacc[2] = {0.f, 0.f};
#pragma unroll
  for (int rb = 0; rb < 2; rb++)
#pragma unroll
    for (int db = 0; db < 4; db++) O[rb][db] = (floatx4)0.0f;

  // A/B pipelined state (register double-buffer, compile-time indexed only)
  bf16x8 pkA[2], pkB[2];
  bf16x8 bVA[4], bVB[4];

// STEP(t): stage(t+1) | ds_read K/V(t) (bV -> OUT set) | PV(t-1) from IN set |
//          QK(t) | exp(t) -> pk OUT set | barrier
#define STEP(t, bufv, IN, OUT, DO_PV, DO_STAGE)                                         \
  do {                                                                                  \
    if (DO_STAGE) STAGE((bufv) ^ 1, (t) + 1);                                           \
    const char* Kb_ = &sbuf[bufv][wk * 4096];                                           \
    const char* Vb_ = &sbuf[bufv][16384 + wk * 4096];                                   \
    f16x8 bK_[2][2];                                                                    \
    _Pragma("unroll") for (int ct = 0; ct < 2; ct++)                                    \
      _Pragma("unroll") for (int ks = 0; ks < 2; ks++)                                  \
        bK_[ct][ks] = *(const f16x8*)(Kb_ + (ct * 2 + ks) * 1024 + lane * 16);          \
    _Pragma("unroll") for (int db = 0; db < 4; db++)                                    \
      bV##OUT[db] = *(const bf16x8*)(Vb_ + db * 1024 + lane * 16);                      \
    __builtin_amdgcn_s_setprio(1);                                                      \
    if (DO_PV) {                                                                        \
      _Pragma("unroll") for (int rb = 0; rb < 2; rb++)                                  \
        _Pragma("unroll") for (int db = 0; db < 4; db++)                                \
          O[rb][db] = __builtin_amdgcn_mfma_f32_16x16x32_bf16(pk##IN[rb], bV##IN[db],   \
                                                              O[rb][db], 0, 0, 0);      \
    }                                                                                   \
    floatx4 St_[2][2];                                                                  \
    _Pragma("unroll") for (int ct = 0; ct < 2; ct++)                                    \
      _Pragma("unroll") for (int rb = 0; rb < 2; rb++) St_[ct][rb] = (floatx4)0.0f;     \
    _Pragma("unroll") for (int ks = 0; ks < 2; ks++)                                    \
      _Pragma("unroll") for (int ct = 0; ct < 2; ct++)                                  \
        _Pragma("unroll") for (int rb = 0; rb < 2; rb++)                                \
          St_[ct][rb] = __builtin_amdgcn_mfma_f32_16x16x32_f16(bK_[ct][ks], aQ[rb][ks], \
                                                               St_[ct][rb], 0, 0, 0);   \
    __builtin_amdgcn_s_setprio(0);                                                      \
    _Pragma("unroll") for (int rb = 0; rb < 2; rb++) {                                  \
      float ps = 0.f;                                                                   \
      _Pragma("unroll") for (int ct = 0; ct < 2; ct++)                                  \
        _Pragma("unroll") for (int r = 0; r < 4; r++) {                                 \
          float p = EXP2(St_[ct][rb][r]);                                               \
          ps += p;                                                                      \
          pk##OUT[rb][ct * 4 + r] = (__bf16)p;                                          \
        }                                                                               \
      lacc[rb] += ps;                                                                   \
    }                                                                                   \
    __syncthreads();                                                                    \
  } while (0)

  STAGE(0, 0);
  __syncthreads();

  // t=0: fills A set, no PV yet
  STEP(0, 0, A, A, 0, 1);
  // pairs (1,2)..(29,30): alternate A->B->A
#pragma unroll 1
  for (int t = 1; t < 31; t += 2) {
    STEP(t, 1, A, B, 1, 1);
    STEP(t + 1, 0, B, A, 1, 1);
  }
  // t=31 (odd, buf1): consumes A, fills B, no stage
  STEP(31, 1, A, B, 1, 0);
  // drain: PV of tile 31
  __builtin_amdgcn_s_setprio(1);
#pragma unroll
  for (int rb = 0; rb < 2; rb++)
#pragma unroll
    for (int db = 0; db < 4; db++)
      O[rb][db] = __builtin_amdgcn_mfma_f32_16x16x32_bf16(pkB[rb], bVB[db], O[rb][db], 0, 0, 0);
  __builtin_amdgcn_s_setprio(0);

  // l partials: reduce across qd lanes; lpart[w][q-local 0..31]
#pragma unroll
  for (int rb = 0; rb < 2; rb++) {
    float v = lacc[rb];
    v += __shfl_xor(v, 16, 64);
    v += __shfl_xor(v, 32, 64);
    if (qd == 0) lpart[w][rb * 16 + ln] = v;
  }

  // epilogue: FULLY UNROLLED (rule #20: runtime rb would home O in scratch)
#pragma unroll
  for (int rb = 0; rb < 2; rb++) {
    __syncthreads();  // rb=0: lpart published + last LDS reads done; rb=1: prior reads done
#pragma unroll
    for (int db = 0; db < 4; db++)
#pragma unroll
      for (int r = 0; r < 4; r++)
        Opart[(w * 16 + qd * 4 + r) * 68 + db * 16 + ln] = O[rb][db][r];
    __syncthreads();
    const int wg2 = tid >> 8;         // 0..1
    const int q2 = (tid >> 4) & 15;   // 0..15
    const int d0 = (tid & 15) * 4;    // 0..60
    float4 s = *(const float4*)&Opart[((wg2 * 4 + 0) * 16 + q2) * 68 + d0];
    const float4 s1 = *(const float4*)&Opart[((wg2 * 4 + 1) * 16 + q2) * 68 + d0];
    const float4 s2 = *(const float4*)&Opart[((wg2 * 4 + 2) * 16 + q2) * 68 + d0];
    const float4 s3 = *(const float4*)&Opart[((wg2 * 4 + 3) * 16 + q2) * 68 + d0];
    float l = lpart[wg2 * 4 + 0][rb * 16 + q2] + lpart[wg2 * 4 + 1][rb * 16 + q2] +
              lpart[wg2 * 4 + 2][rb * 16 + q2] + lpart[wg2 * 4 + 3][rb * 16 + q2];
    const float inv = 1.0f / l;
    float4 o;
    o.x = (s.x + s1.x + s2.x + s3.x) * inv;
    o.y = (s.y + s1.y + s2.y + s3.y) * inv;
    o.z = (s.z + s1.z + s2.z + s3.z) * inv;
    o.w = (s.w + s1.w + s2.w + s3.w) * inv;
    *(float4*)(out + bbase + (long)(q0 + wg2 * 32 + rb * 16 + q2) * DIM + d0) = o;
  }
#undef STEP
#undef STAGE
}

extern "C" void kernel_launch(void* const* d_in, const int* in_sizes, int n_in,
                              void* d_out, int out_size, void* d_ws, size_t ws_size,
                              hipStream_t stream) {
  const float* X = (const float*)d_in[0];
  const float* W = (const float*)d_in[1];
  float* out = (float*)d_out;
  const size_t SZ = (size_t)B_N * T_SEQ * DIM * 2;  // 4 MB per u16 array
  u16* Kswz = (u16*)d_ws;
  u16* Qswz = (u16*)((char*)d_ws + SZ);
  u16* Vswz = (u16*)((char*)d_ws + 2 * SZ);
  prep_kernel<<<dim3(T_SEQ / 32, B_N), 256, 0, stream>>>(X, W, Kswz, Qswz, Vswz);
  attn_kernel<<<dim3(B_N * (T_SEQ / QT)), 512, 0, stream>>>(Kswz, Qswz, Vswz, out);
}

// Round 8
// 110.013 us; speedup vs baseline: 1.2815x; 1.2815x over previous
//
#include <hip/hip_runtime.h>

typedef _Float16 f16;
typedef _Float16 f16x8 __attribute__((ext_vector_type(8)));
typedef __bf16 bf16x8 __attribute__((ext_vector_type(8)));
typedef float floatx4 __attribute__((ext_vector_type(4)));
typedef unsigned short u16;

#define B_N   8
#define T_SEQ 4096
#define DIM   64
#define QT    64     // q rows per attn block
#define NIT   32     // 4096 / (128 keys per iter: 32 per wave x 4 key-subgroup waves)
#define XSTR  72     // prep LDS row stride in u16
#define LOG2E 1.44269504f
#define FRAG  512    // fragment = 512 u16 (1 KB): lane holds its 8 u16 at lane*8

#if __has_builtin(__builtin_amdgcn_exp2f)
#define EXP2(x) __builtin_amdgcn_exp2f(x)
#else
#define EXP2(x) exp2f(x)
#endif

typedef __attribute__((address_space(1))) const void gvoid;
typedef __attribute__((address_space(3))) void svoid;

// ---- prep v2: 32-row blocks, wave-specialized roles. Unchanged from round 6. ----
__launch_bounds__(256, 4)
__global__ void prep_kernel(const float* __restrict__ X, const float* __restrict__ W,
                            u16* __restrict__ Kswz, u16* __restrict__ Qswz,
                            u16* __restrict__ Vswz) {
  __shared__ __attribute__((aligned(16))) u16 Xs[32 * XSTR];      // f16 X tile [t][d]
  __shared__ __attribute__((aligned(16))) u16 Wt[DIM * XSTR];     // f16 W^T [e][d]
  __shared__ __attribute__((aligned(16))) u16 Qs[2][16 * XSTR];   // f16 Q rows (per Q-wave)
  const int tid = threadIdx.x;
  const int lane = tid & 63, w = tid >> 6, qd = lane >> 4, ln = lane & 15;
  const int b = blockIdx.y;
  const int tau = blockIdx.x;                 // global 32-row tile index, 0..127
  const long xbase = ((long)b * T_SEQ + tau * 32) * DIM;

  {
    // X tile: 32 rows x 64 cols, 8 f32 per thread
    const int r = tid >> 3, c0 = (tid & 7) * 8;
    float v[8];
    *(float4*)&v[0] = *(const float4*)(X + xbase + (long)r * DIM + c0);
    *(float4*)&v[4] = *(const float4*)(X + xbase + (long)r * DIM + c0 + 4);
    u16 h[8];
#pragma unroll
    for (int j = 0; j < 8; j++) h[j] = __builtin_bit_cast(u16, (f16)v[j]);
    *(uint4*)&Xs[r * XSTR + c0] = *(uint4*)&h[0];
    // W: 64x64, 16 f32 per thread, transposed scalar stores
    const int r2 = tid >> 2, c2 = (tid & 3) * 16;
    float wv[16];
#pragma unroll
    for (int i = 0; i < 4; i++)
      *(float4*)&wv[i * 4] = *(const float4*)(W + r2 * DIM + c2 + i * 4);
#pragma unroll
    for (int j = 0; j < 16; j++) Wt[(c2 + j) * XSTR + r2] = __builtin_bit_cast(u16, (f16)wv[j]);
  }
  __syncthreads();

  if (w == 0) {
    // K fragments, SLOT-PERMUTED: frag (tau, ct), lane ln reads tile-local row
    // krow = (ln>>2)*8 + ct*4 + (ln&3).
#pragma unroll
    for (int ct = 0; ct < 2; ct++) {
      const int krow = (ln >> 2) * 8 + ct * 4 + (ln & 3);
      const long F = ((long)b * 128 + tau) * 2 + ct;
#pragma unroll
      for (int ks = 0; ks < 2; ks++) {
        f16x8 kv = *(const f16x8*)&Xs[krow * XSTR + ks * 32 + qd * 8];
        *(f16x8*)(Kswz + (F * 2 + ks) * FRAG + lane * 8) = kv;
      }
    }
    // V d-block 0
    {
      const long Cb = (long)b * 4 + 0;
      bf16x8 vv;
#pragma unroll
      for (int j = 0; j < 8; j++) {
        f16 hv = __builtin_bit_cast(f16, Xs[(qd * 8 + j) * XSTR + 0 * 16 + ln]);
        vv[j] = (__bf16)(float)hv;
      }
      *(bf16x8*)(Vswz + (Cb * (T_SEQ / 32) + tau) * FRAG + lane * 8) = vv;
    }
  } else if (w == 1) {
    // V d-blocks 1..3
#pragma unroll
    for (int db = 1; db < 4; db++) {
      const long Cb = (long)b * 4 + db;
      bf16x8 vv;
#pragma unroll
      for (int j = 0; j < 8; j++) {
        f16 hv = __builtin_bit_cast(f16, Xs[(qd * 8 + j) * XSTR + db * 16 + ln]);
        vv[j] = (__bf16)(float)hv;
      }
      *(bf16x8*)(Vswz + (Cb * (T_SEQ / 32) + tau) * FRAG + lane * 8) = vv;
    }
  } else {
    // Q rows (w-2)*16 .. +16: X@W via MFMA, scale by log2e, emit A-fragments
    const int h2 = w - 2;             // 0..1
    const int rq = h2 * 16;
    floatx4 acc[4];
#pragma unroll
    for (int ct = 0; ct < 4; ct++) acc[ct] = (floatx4)0.0f;
#pragma unroll
    for (int ks = 0; ks < 2; ks++) {
      f16x8 aX = *(const f16x8*)&Xs[(rq + ln) * XSTR + ks * 32 + qd * 8];
#pragma unroll
      for (int ct = 0; ct < 4; ct++) {
        f16x8 bW = *(const f16x8*)&Wt[(ct * 16 + ln) * XSTR + ks * 32 + qd * 8];
        acc[ct] = __builtin_amdgcn_mfma_f32_16x16x32_f16(aX, bW, acc[ct], 0, 0, 0);
      }
    }
#pragma unroll
    for (int ct = 0; ct < 4; ct++)
#pragma unroll
      for (int r = 0; r < 4; r++)
        Qs[h2][(qd * 4 + r) * XSTR + ct * 16 + ln] =
            __builtin_bit_cast(u16, (f16)(acc[ct][r] * LOG2E));
    // wave-local rows: no barrier needed
    const long R = (long)b * (T_SEQ / 16) + tau * 2 + h2;
#pragma unroll
    for (int ks = 0; ks < 2; ks++) {
      f16x8 qv = *(const f16x8*)&Qs[h2][ln * XSTR + ks * 32 + qd * 8];
      *(f16x8*)(Qswz + (R * 2 + ks) * FRAG + lane * 8) = qv;
    }
  }
}

// ---- main: 8 waves = 2 q-groups x 4 key-subgroups. K/V staged to LDS via
// global_load_lds (double-buffered, 1 barrier/iter). P in registers.
// ROUND 8: software pipeline retained (PV(t-1) at top, register-only MFMA
// covering ds_read latency of tile t), but register-budget-fixed:
//  - __launch_bounds__(512, 2): round 7's (512,4) imposed a 64-VGPR cap
//    (32 waves/CU target) -> compiler spilled the pipeline state, 30 MB of
//    phantom scratch writes (WRITE_SIZE 38912 KB). LDS limits us to 2
//    blocks/CU anyway, so (512,2) costs nothing and doubles the reg budget.
//  - single pk set: PV(t-1) reads pk BEFORE exp(t) overwrites it (WAR in
//    program order). Saves 8 VGPR vs pkA/pkB. bV stays double-buffered.
// Rule #20 discipline throughout: all reg-array indices compile-time.
__launch_bounds__(512, 2)
__global__ void attn_kernel(const u16* __restrict__ Kswz, const u16* __restrict__ Qswz,
                            const u16* __restrict__ Vswz, float* __restrict__ out) {
  // staging: per buf 32 KB = 16 K-frags (16 KB) + 16 V-frags (16 KB), 1 KB each
  __shared__ __attribute__((aligned(16))) char sbuf[2][32768];
  __shared__ float lpart[8][32];
  float* Opart = (float*)&sbuf[0][0];  // epilogue alias: 8*16*68*4 = 34816 B <= 65536

  const int tid = threadIdx.x;
  const int lane = tid & 63;
  const int w = tid >> 6;           // 0..7
  const int qd = lane >> 4;
  const int ln = lane & 15;
  const int wg = w >> 2;            // q-group
  const int wk = w & 3;             // key subgroup
  const int bid = blockIdx.x;
  const int b = bid & 7;            // batch == XCD for L2 affinity
  const int q0 = (bid >> 3) * QT;
  const long bbase = (long)b * T_SEQ * DIM;

  // Q B-fragments pinned: 32 rows x 64 d for this q-group
  f16x8 aQ[2][2];
#pragma unroll
  for (int rb = 0; rb < 2; rb++)
#pragma unroll
    for (int ks = 0; ks < 2; ks++)
      aQ[rb][ks] = *(const f16x8*)(Qswz +
          (((long)b * (T_SEQ / 16) + (q0 >> 4) + wg * 2 + rb) * 2 + ks) * FRAG + lane * 8);

  // staging source bases (per-lane byte pointers)
  const char* gKw = (const char*)Kswz + (long)b * 524288 + (long)w * 4096 + lane * 16;
  const char* gVw = (const char*)Vswz + (long)b * 524288 + (long)(w - 4) * 1024 + lane * 16;

#define STAGE(bufv, t)                                                                  \
  do {                                                                                  \
    if (w < 4) {                                                                        \
      const char* g = gKw + (long)(t) * 16384;                                          \
      char* l = &sbuf[bufv][w * 4096];                                                  \
      _Pragma("unroll") for (int i = 0; i < 4; i++)                                     \
          __builtin_amdgcn_global_load_lds((gvoid*)(g + i * 1024), (svoid*)(l + i * 1024), \
                                           16, 0, 0);                                   \
    } else {                                                                            \
      const char* g = gVw + (long)(t) * 4096;                                           \
      char* l = &sbuf[bufv][16384 + (w - 4) * 4096];                                    \
      _Pragma("unroll") for (int i = 0; i < 4; i++)                                     \
          __builtin_amdgcn_global_load_lds((gvoid*)(g + i * 131072), (svoid*)(l + i * 1024), \
                                           16, 0, 0);                                   \
    }                                                                                   \
  } while (0)

  floatx4 O[2][4];                  // [q 16-block][d 16-block], 32q x 64d per wave
  float lacc[2] = {0.f, 0.f};
#pragma unroll
  for (int rb = 0; rb < 2; rb++)
#pragma unroll
    for (int db = 0; db < 4; db++) O[rb][db] = (floatx4)0.0f;

  // pipelined state: single pk (P of tile t-1), double-buffered bV
  bf16x8 pk[2];
  bf16x8 bVA[4], bVB[4];

// STEP(t): stage(t+1) | ds_read K(t), V(t)->bV OUT | PV(t-1) from pk+bV IN |
//          QK(t) | exp(t) overwrites pk | barrier.  (PV reads pk before exp
//          redefines it — single-set WAR, no double buffer needed.)
#define STEP(t, bufv, IN, OUT, DO_PV, DO_STAGE)                                         \
  do {                                                                                  \
    if (DO_STAGE) STAGE((bufv) ^ 1, (t) + 1);                                           \
    const char* Kb_ = &sbuf[bufv][wk * 4096];                                           \
    const char* Vb_ = &sbuf[bufv][16384 + wk * 4096];                                   \
    f16x8 bK_[2][2];                                                                    \
    _Pragma("unroll") for (int ct = 0; ct < 2; ct++)                                    \
      _Pragma("unroll") for (int ks = 0; ks < 2; ks++)                                  \
        bK_[ct][ks] = *(const f16x8*)(Kb_ + (ct * 2 + ks) * 1024 + lane * 16);          \
    _Pragma("unroll") for (int db = 0; db < 4; db++)                                    \
      bV##OUT[db] = *(const bf16x8*)(Vb_ + db * 1024 + lane * 16);                      \
    __builtin_amdgcn_s_setprio(1);                                                      \
    if (DO_PV) {                                                                        \
      _Pragma("unroll") for (int rb = 0; rb < 2; rb++)                                  \
        _Pragma("unroll") for (int db = 0; db < 4; db++)                                \
          O[rb][db] = __builtin_amdgcn_mfma_f32_16x16x32_bf16(pk[rb], bV##IN[db],       \
                                                              O[rb][db], 0, 0, 0);      \
    }                                                                                   \
    floatx4 St_[2][2];                                                                  \
    _Pragma("unroll") for (int ct = 0; ct < 2; ct++)                                    \
      _Pragma("unroll") for (int rb = 0; rb < 2; rb++) St_[ct][rb] = (floatx4)0.0f;     \
    _Pragma("unroll") for (int ks = 0; ks < 2; ks++)                                    \
      _Pragma("unroll") for (int ct = 0; ct < 2; ct++)                                  \
        _Pragma("unroll") for (int rb = 0; rb < 2; rb++)                                \
          St_[ct][rb] = __builtin_amdgcn_mfma_f32_16x16x32_f16(bK_[ct][ks], aQ[rb][ks], \
                                                               St_[ct][rb], 0, 0, 0);   \
    __builtin_amdgcn_s_setprio(0);                                                      \
    _Pragma("unroll") for (int rb = 0; rb < 2; rb++) {                                  \
      float ps = 0.f;                                                                   \
      _Pragma("unroll") for (int ct = 0; ct < 2; ct++)                                  \
        _Pragma("unroll") for (int r = 0; r < 4; r++) {                                 \
          float p = EXP2(St_[ct][rb][r]);                                               \
          ps += p;                                                                      \
          pk[rb][ct * 4 + r] = (__bf16)p;                                               \
        }                                                                               \
      lacc[rb] += ps;                                                                   \
    }                                                                                   \
    __syncthreads();                                                                    \
  } while (0)

  STAGE(0, 0);
  __syncthreads();

  // t=0: fills bVA + pk(P0), no PV yet
  STEP(0, 0, A, A, 0, 1);
  // pairs (1,2)..(29,30): odd t consumes A fills B; even t consumes B fills A
#pragma unroll 1
  for (int t = 1; t < 31; t += 2) {
    STEP(t, 1, A, B, 1, 1);
    STEP(t + 1, 0, B, A, 1, 1);
  }
  // t=31 (odd, buf1): PV(30) from A, fills bVB + pk(P31), no stage
  STEP(31, 1, A, B, 1, 0);
  // drain: PV of tile 31
  __builtin_amdgcn_s_setprio(1);
#pragma unroll
  for (int rb = 0; rb < 2; rb++)
#pragma unroll
    for (int db = 0; db < 4; db++)
      O[rb][db] = __builtin_amdgcn_mfma_f32_16x16x32_bf16(pk[rb], bVB[db], O[rb][db], 0, 0, 0);
  __builtin_amdgcn_s_setprio(0);

  // l partials: reduce across qd lanes; lpart[w][q-local 0..31]
#pragma unroll
  for (int rb = 0; rb < 2; rb++) {
    float v = lacc[rb];
    v += __shfl_xor(v, 16, 64);
    v += __shfl_xor(v, 32, 64);
    if (qd == 0) lpart[w][rb * 16 + ln] = v;
  }

  // epilogue: FULLY UNROLLED (rule #20: runtime rb would home O in scratch)
#pragma unroll
  for (int rb = 0; rb < 2; rb++) {
    __syncthreads();  // rb=0: lpart published + last LDS reads done; rb=1: prior reads done
#pragma unroll
    for (int db = 0; db < 4; db++)
#pragma unroll
      for (int r = 0; r < 4; r++)
        Opart[(w * 16 + qd * 4 + r) * 68 + db * 16 + ln] = O[rb][db][r];
    __syncthreads();
    const int wg2 = tid >> 8;         // 0..1
    const int q2 = (tid >> 4) & 15;   // 0..15
    const int d0 = (tid & 15) * 4;    // 0..60
    float4 s = *(const float4*)&Opart[((wg2 * 4 + 0) * 16 + q2) * 68 + d0];
    const float4 s1 = *(const float4*)&Opart[((wg2 * 4 + 1) * 16 + q2) * 68 + d0];
    const float4 s2 = *(const float4*)&Opart[((wg2 * 4 + 2) * 16 + q2) * 68 + d0];
    const float4 s3 = *(const float4*)&Opart[((wg2 * 4 + 3) * 16 + q2) * 68 + d0];
    float l = lpart[wg2 * 4 + 0][rb * 16 + q2] + lpart[wg2 * 4 + 1][rb * 16 + q2] +
              lpart[wg2 * 4 + 2][rb * 16 + q2] + lpart[wg2 * 4 + 3][rb * 16 + q2];
    const float inv = 1.0f / l;
    float4 o;
    o.x = (s.x + s1.x + s2.x + s3.x) * inv;
    o.y = (s.y + s1.y + s2.y + s3.y) * inv;
    o.z = (s.z + s1.z + s2.z + s3.z) * inv;
    o.w = (s.w + s1.w + s2.w + s3.w) * inv;
    *(float4*)(out + bbase + (long)(q0 + wg2 * 32 + rb * 16 + q2) * DIM + d0) = o;
  }
#undef STEP
#undef STAGE
}

extern "C" void kernel_launch(void* const* d_in, const int* in_sizes, int n_in,
                              void* d_out, int out_size, void* d_ws, size_t ws_size,
                              hipStream_t stream) {
  const float* X = (const float*)d_in[0];
  const float* W = (const float*)d_in[1];
  float* out = (float*)d_out;
  const size_t SZ = (size_t)B_N * T_SEQ * DIM * 2;  // 4 MB per u16 array
  u16* Kswz = (u16*)d_ws;
  u16* Qswz = (u16*)((char*)d_ws + SZ);
  u16* Vswz = (u16*)((char*)d_ws + 2 * SZ);
  prep_kernel<<<dim3(T_SEQ / 32, B_N), 256, 0, stream>>>(X, W, Kswz, Qswz, Vswz);
  attn_kernel<<<dim3(B_N * (T_SEQ / QT)), 512, 0, stream>>>(Kswz, Qswz, Vswz, out);
}

// Round 9
// 104.205 us; speedup vs baseline: 1.3529x; 1.0557x over previous
//
#include <hip/hip_runtime.h>

typedef _Float16 f16;
typedef _Float16 f16x8 __attribute__((ext_vector_type(8)));
typedef __bf16 bf16x8 __attribute__((ext_vector_type(8)));
typedef float floatx4 __attribute__((ext_vector_type(4)));
typedef unsigned short u16;

#define B_N   8
#define T_SEQ 4096
#define DIM   64
#define QT    64     // q rows per attn block
#define NIT   32     // 4096 / (128 keys per iter: 32 per wave x 4 key-subgroup waves)
#define XSTR  72     // prep LDS row stride in u16
#define LOG2E 1.44269504f
#define FRAG  512    // fragment = 512 u16 (1 KB): lane holds its 8 u16 at lane*8

#if __has_builtin(__builtin_amdgcn_exp2f)
#define EXP2(x) __builtin_amdgcn_exp2f(x)
#else
#define EXP2(x) exp2f(x)
#endif

typedef __attribute__((address_space(1))) const void gvoid;
typedef __attribute__((address_space(3))) void svoid;

// ---- prep v2: 32-row blocks, wave-specialized roles. Unchanged from round 6. ----
__launch_bounds__(256, 4)
__global__ void prep_kernel(const float* __restrict__ X, const float* __restrict__ W,
                            u16* __restrict__ Kswz, u16* __restrict__ Qswz,
                            u16* __restrict__ Vswz) {
  __shared__ __attribute__((aligned(16))) u16 Xs[32 * XSTR];      // f16 X tile [t][d]
  __shared__ __attribute__((aligned(16))) u16 Wt[DIM * XSTR];     // f16 W^T [e][d]
  __shared__ __attribute__((aligned(16))) u16 Qs[2][16 * XSTR];   // f16 Q rows (per Q-wave)
  const int tid = threadIdx.x;
  const int lane = tid & 63, w = tid >> 6, qd = lane >> 4, ln = lane & 15;
  const int b = blockIdx.y;
  const int tau = blockIdx.x;                 // global 32-row tile index, 0..127
  const long xbase = ((long)b * T_SEQ + tau * 32) * DIM;

  {
    // X tile: 32 rows x 64 cols, 8 f32 per thread
    const int r = tid >> 3, c0 = (tid & 7) * 8;
    float v[8];
    *(float4*)&v[0] = *(const float4*)(X + xbase + (long)r * DIM + c0);
    *(float4*)&v[4] = *(const float4*)(X + xbase + (long)r * DIM + c0 + 4);
    u16 h[8];
#pragma unroll
    for (int j = 0; j < 8; j++) h[j] = __builtin_bit_cast(u16, (f16)v[j]);
    *(uint4*)&Xs[r * XSTR + c0] = *(uint4*)&h[0];
    // W: 64x64, 16 f32 per thread, transposed scalar stores
    const int r2 = tid >> 2, c2 = (tid & 3) * 16;
    float wv[16];
#pragma unroll
    for (int i = 0; i < 4; i++)
      *(float4*)&wv[i * 4] = *(const float4*)(W + r2 * DIM + c2 + i * 4);
#pragma unroll
    for (int j = 0; j < 16; j++) Wt[(c2 + j) * XSTR + r2] = __builtin_bit_cast(u16, (f16)wv[j]);
  }
  __syncthreads();

  if (w == 0) {
    // K fragments, SLOT-PERMUTED: frag (tau, ct), lane ln reads tile-local row
    // krow = (ln>>2)*8 + ct*4 + (ln&3).
#pragma unroll
    for (int ct = 0; ct < 2; ct++) {
      const int krow = (ln >> 2) * 8 + ct * 4 + (ln & 3);
      const long F = ((long)b * 128 + tau) * 2 + ct;
#pragma unroll
      for (int ks = 0; ks < 2; ks++) {
        f16x8 kv = *(const f16x8*)&Xs[krow * XSTR + ks * 32 + qd * 8];
        *(f16x8*)(Kswz + (F * 2 + ks) * FRAG + lane * 8) = kv;
      }
    }
    // V d-block 0
    {
      const long Cb = (long)b * 4 + 0;
      bf16x8 vv;
#pragma unroll
      for (int j = 0; j < 8; j++) {
        f16 hv = __builtin_bit_cast(f16, Xs[(qd * 8 + j) * XSTR + 0 * 16 + ln]);
        vv[j] = (__bf16)(float)hv;
      }
      *(bf16x8*)(Vswz + (Cb * (T_SEQ / 32) + tau) * FRAG + lane * 8) = vv;
    }
  } else if (w == 1) {
    // V d-blocks 1..3
#pragma unroll
    for (int db = 1; db < 4; db++) {
      const long Cb = (long)b * 4 + db;
      bf16x8 vv;
#pragma unroll
      for (int j = 0; j < 8; j++) {
        f16 hv = __builtin_bit_cast(f16, Xs[(qd * 8 + j) * XSTR + db * 16 + ln]);
        vv[j] = (__bf16)(float)hv;
      }
      *(bf16x8*)(Vswz + (Cb * (T_SEQ / 32) + tau) * FRAG + lane * 8) = vv;
    }
  } else {
    // Q rows (w-2)*16 .. +16: X@W via MFMA, scale by log2e, emit A-fragments
    const int h2 = w - 2;             // 0..1
    const int rq = h2 * 16;
    floatx4 acc[4];
#pragma unroll
    for (int ct = 0; ct < 4; ct++) acc[ct] = (floatx4)0.0f;
#pragma unroll
    for (int ks = 0; ks < 2; ks++) {
      f16x8 aX = *(const f16x8*)&Xs[(rq + ln) * XSTR + ks * 32 + qd * 8];
#pragma unroll
      for (int ct = 0; ct < 4; ct++) {
        f16x8 bW = *(const f16x8*)&Wt[(ct * 16 + ln) * XSTR + ks * 32 + qd * 8];
        acc[ct] = __builtin_amdgcn_mfma_f32_16x16x32_f16(aX, bW, acc[ct], 0, 0, 0);
      }
    }
#pragma unroll
    for (int ct = 0; ct < 4; ct++)
#pragma unroll
      for (int r = 0; r < 4; r++)
        Qs[h2][(qd * 4 + r) * XSTR + ct * 16 + ln] =
            __builtin_bit_cast(u16, (f16)(acc[ct][r] * LOG2E));
    // wave-local rows: no barrier needed
    const long R = (long)b * (T_SEQ / 16) + tau * 2 + h2;
#pragma unroll
    for (int ks = 0; ks < 2; ks++) {
      f16x8 qv = *(const f16x8*)&Qs[h2][ln * XSTR + ks * 32 + qd * 8];
      *(f16x8*)(Qswz + (R * 2 + ks) * FRAG + lane * 8) = qv;
    }
  }
}

// ---- main, ROUND 9: r6 structure (best verified: 47.6 us), occupancy-fixed.
// K staged to LDS (double-buffered, all 8 waves stage 2 KB each); V read
// DIRECTLY from global (L2-resident, b==XCD) into registers, issued at the
// TOP of the iteration so QK+exp cover the L2 latency and PV's vmcnt wait
// does not drain the stage loads (V loads are oldest). LDS 65->36 KB ->
// 3-4 blocks/CU (was 2): more cross-block phase slip to fill idle issue
// slots. Cross-iteration pipelining abandoned (r7 spilled, r8 slower).
// Rule #20: all register-array indices compile-time.
__launch_bounds__(512, 4)
__global__ void attn_kernel(const u16* __restrict__ Kswz, const u16* __restrict__ Qswz,
                            const u16* __restrict__ Vswz, float* __restrict__ out) {
  // smem: K dbuf 2 x 16 KB during main loop; epilogue Opart (34816 B) aliases
  __shared__ __attribute__((aligned(16))) char smem[35840];
  __shared__ float lpart[8][32];
  float* Opart = (float*)smem;

  const int tid = threadIdx.x;
  const int lane = tid & 63;
  const int w = tid >> 6;           // 0..7
  const int qd = lane >> 4;
  const int ln = lane & 15;
  const int wg = w >> 2;            // q-group
  const int wk = w & 3;             // key subgroup
  const int bid = blockIdx.x;
  const int b = bid & 7;            // batch == XCD for L2 affinity
  const int q0 = (bid >> 3) * QT;
  const long bbase = (long)b * T_SEQ * DIM;

  // Q B-fragments pinned: 32 rows x 64 d for this q-group
  f16x8 aQ[2][2];
#pragma unroll
  for (int rb = 0; rb < 2; rb++)
#pragma unroll
    for (int ks = 0; ks < 2; ks++)
      aQ[rb][ks] = *(const f16x8*)(Qswz +
          (((long)b * (T_SEQ / 16) + (q0 >> 4) + wg * 2 + rb) * 2 + ks) * FRAG + lane * 8);

  // K stage source: wave w stages frags w*2, w*2+1 of the 16 per tile-group
  // (frag f of group t at byte b*524288 + t*16384 + f*1024)
  const char* gKw = (const char*)Kswz + (long)b * 524288 + (long)w * 2048 + lane * 16;
  // V direct source: frag (db, tile t*4+wk) at b*524288 + db*131072 + (t*4+wk)*1024
  const char* gV = (const char*)Vswz + (long)b * 524288 + (long)wk * 1024 + lane * 16;

#define STAGE(bufv, t)                                                                  \
  do {                                                                                  \
    const char* g = gKw + (long)(t) * 16384;                                            \
    char* l = smem + (bufv) * 16384 + w * 2048;                                         \
    __builtin_amdgcn_global_load_lds((gvoid*)(g), (svoid*)(l), 16, 0, 0);               \
    __builtin_amdgcn_global_load_lds((gvoid*)(g + 1024), (svoid*)(l + 1024), 16, 0, 0); \
  } while (0)

  floatx4 O[2][4];                  // [q 16-block][d 16-block], 32q x 64d per wave
  float lacc[2] = {0.f, 0.f};
#pragma unroll
  for (int rb = 0; rb < 2; rb++)
#pragma unroll
    for (int db = 0; db < 4; db++) O[rb][db] = (floatx4)0.0f;

  STAGE(0, 0);
  __syncthreads();

  int buf = 0;
#pragma unroll 1
  for (int t = 0; t < NIT; t++) {
    // V fragments: global loads FIRST (oldest in vmcnt queue -> PV's wait
    // leaves the younger stage loads outstanding)
    bf16x8 bV[4];
#pragma unroll
    for (int db = 0; db < 4; db++)
      bV[db] = *(const bf16x8*)(gV + (long)t * 4096 + (long)db * 131072);

    // prefetch next K tile-group into the other buffer (async)
    if (t + 1 < NIT) STAGE(buf ^ 1, t + 1);

    // K LDS -> registers (linear 1 KB fragments: conflict-free b128 reads)
    const char* Kb = smem + buf * 16384 + wk * 4096;
    f16x8 bK[2][2];
#pragma unroll
    for (int ct = 0; ct < 2; ct++)
#pragma unroll
      for (int ks = 0; ks < 2; ks++)
        bK[ct][ks] = *(const f16x8*)(Kb + (ct * 2 + ks) * 1024 + lane * 16);

    // QK^T: S^T[32k x 32q]
    floatx4 St[2][2];
#pragma unroll
    for (int ct = 0; ct < 2; ct++)
#pragma unroll
      for (int rb = 0; rb < 2; rb++) St[ct][rb] = (floatx4)0.0f;
    __builtin_amdgcn_s_setprio(1);
#pragma unroll
    for (int ks = 0; ks < 2; ks++)
#pragma unroll
      for (int ct = 0; ct < 2; ct++)
#pragma unroll
        for (int rb = 0; rb < 2; rb++)
          St[ct][rb] = __builtin_amdgcn_mfma_f32_16x16x32_f16(bK[ct][ks], aQ[rb][ks], St[ct][rb], 0, 0, 0);
    __builtin_amdgcn_s_setprio(0);

    // P = 2^S' in registers: slot (ct,qd,r) -> A-frag element j = ct*4 + r
    bf16x8 pk[2];
#pragma unroll
    for (int rb = 0; rb < 2; rb++) {
      float ps = 0.f;
#pragma unroll
      for (int ct = 0; ct < 2; ct++)
#pragma unroll
        for (int r = 0; r < 4; r++) {
          float p = EXP2(St[ct][rb][r]);
          ps += p;
          pk[rb][ct * 4 + r] = (__bf16)p;
        }
      lacc[rb] += ps;
    }

    // PV: O[32q x 64d] += P[32q x 32k] V[32k x 64d]
    __builtin_amdgcn_s_setprio(1);
#pragma unroll
    for (int rb = 0; rb < 2; rb++)
#pragma unroll
      for (int db = 0; db < 4; db++)
        O[rb][db] = __builtin_amdgcn_mfma_f32_16x16x32_bf16(pk[rb], bV[db], O[rb][db], 0, 0, 0);
    __builtin_amdgcn_s_setprio(0);

    __syncthreads();  // drains vmcnt (next K tile staged) + lgkm; publishes buf^1
    buf ^= 1;
  }

  // l partials: reduce across qd lanes; lpart[w][q-local 0..31]
#pragma unroll
  for (int rb = 0; rb < 2; rb++) {
    float v = lacc[rb];
    v += __shfl_xor(v, 16, 64);
    v += __shfl_xor(v, 32, 64);
    if (qd == 0) lpart[w][rb * 16 + ln] = v;
  }

  // epilogue: FULLY UNROLLED (rule #20: runtime rb would home O in scratch)
#pragma unroll
  for (int rb = 0; rb < 2; rb++) {
    __syncthreads();  // rb=0: lpart published + last K reads done; rb=1: prior reads done
#pragma unroll
    for (int db = 0; db < 4; db++)
#pragma unroll
      for (int r = 0; r < 4; r++)
        Opart[(w * 16 + qd * 4 + r) * 68 + db * 16 + ln] = O[rb][db][r];
    __syncthreads();
    const int wg2 = tid >> 8;         // 0..1
    const int q2 = (tid >> 4) & 15;   // 0..15
    const int d0 = (tid & 15) * 4;    // 0..60
    float4 s = *(const float4*)&Opart[((wg2 * 4 + 0) * 16 + q2) * 68 + d0];
    const float4 s1 = *(const float4*)&Opart[((wg2 * 4 + 1) * 16 + q2) * 68 + d0];
    const float4 s2 = *(const float4*)&Opart[((wg2 * 4 + 2) * 16 + q2) * 68 + d0];
    const float4 s3 = *(const float4*)&Opart[((wg2 * 4 + 3) * 16 + q2) * 68 + d0];
    float l = lpart[wg2 * 4 + 0][rb * 16 + q2] + lpart[wg2 * 4 + 1][rb * 16 + q2] +
              lpart[wg2 * 4 + 2][rb * 16 + q2] + lpart[wg2 * 4 + 3][rb * 16 + q2];
    const float inv = 1.0f / l;
    float4 o;
    o.x = (s.x + s1.x + s2.x + s3.x) * inv;
    o.y = (s.y + s1.y + s2.y + s3.y) * inv;
    o.z = (s.z + s1.z + s2.z + s3.z) * inv;
    o.w = (s.w + s1.w + s2.w + s3.w) * inv;
    *(float4*)(out + bbase + (long)(q0 + wg2 * 32 + rb * 16 + q2) * DIM + d0) = o;
  }
#undef STAGE
}

extern "C" void kernel_launch(void* const* d_in, const int* in_sizes, int n_in,
                              void* d_out, int out_size, void* d_ws, size_t ws_size,
                              hipStream_t stream) {
  const float* X = (const float*)d_in[0];
  const float* W = (const float*)d_in[1];
  float* out = (float*)d_out;
  const size_t SZ = (size_t)B_N * T_SEQ * DIM * 2;  // 4 MB per u16 array
  u16* Kswz = (u16*)d_ws;
  u16* Qswz = (u16*)((char*)d_ws + SZ);
  u16* Vswz = (u16*)((char*)d_ws + 2 * SZ);
  prep_kernel<<<dim3(T_SEQ / 32, B_N), 256, 0, stream>>>(X, W, Kswz, Qswz, Vswz);
  attn_kernel<<<dim3(B_N * (T_SEQ / QT)), 512, 0, stream>>>(Kswz, Qswz, Vswz, out);
}